// Round 8
// baseline (550.942 us; speedup 1.0000x reference)
//
#include <hip/hip_runtime.h>
#include <hip/hip_bf16.h>

#define T_TOK 2048
#define DIM 1024
#define HEADS 8
#define QK_HD 128
#define V_HD 128
#define NOPE 64
#define ROPE 64
#define KV_LORA 256
#define N_EXP 32
#define TOPK 4
#define INTER 512
#define S_LEN 1024
#define KVP_W (HEADS * (NOPE + V_HD))   // 1536

typedef __attribute__((ext_vector_type(8))) _Float16 f16x8;
typedef __attribute__((ext_vector_type(4))) float f32x4;

__device__ inline unsigned short f2h(float f) {
  union { _Float16 h; unsigned short u; } c;
  c.h = (_Float16)f;
  return c.u;
}
__device__ inline float h2f(unsigned short u) {
  union { _Float16 h; unsigned short u; } c;
  c.u = u;
  return (float)c.h;
}

// XOR swizzle mask for a [64][64] f16 LDS tile (16B-chunk granular). Verified R5.
__device__ inline int smask(int row) { return (row & 7) ^ ((row & 3) << 1); }
__device__ inline int swz(int row, int col) {
  return row * 64 + (col ^ (smask(row) << 3));
}

// async global->LDS, 16B per lane. LDS dest is wave-uniform base + lane*16 (HW);
// global src is per-lane. Swizzled layout achieved by pre-swizzling the source col.
__device__ inline void gl16(const void* g, void* l) {
  __builtin_amdgcn_global_load_lds(
      (const __attribute__((address_space(1))) void*)g,
      (__attribute__((address_space(3))) void*)l, 16, 0, 0);
}

// ---------------- transpose + f32->f16 convert: dst[n][k] = src[k][n] ----------------
// grid: (N/32, K/32, E), block 256
__launch_bounds__(256)
__global__ void tcvt_k(const float* __restrict__ src, unsigned short* __restrict__ dst,
                       int K, int N) {
  int e = blockIdx.z;
  src += (size_t)e * K * N;
  dst += (size_t)e * K * N;
  int n0 = blockIdx.x * 32, k0 = blockIdx.y * 32;
  __shared__ float ts[32][33];
  int tid = threadIdx.x;
  int r = tid >> 3, c4 = (tid & 7) * 4;
  float4 v = *(const float4*)(src + (size_t)(k0 + r) * N + n0 + c4);
  ts[r][c4] = v.x; ts[r][c4 + 1] = v.y; ts[r][c4 + 2] = v.z; ts[r][c4 + 3] = v.w;
  __syncthreads();
  ushort4 o;
  o.x = f2h(ts[c4][r]);
  o.y = f2h(ts[c4 + 1][r]);
  o.z = f2h(ts[c4 + 2][r]);
  o.w = f2h(ts[c4 + 3][r]);
  *(ushort4*)(dst + (size_t)(n0 + r) * K + k0 + c4) = o;
}

__launch_bounds__(64)
__global__ void zero_counters_k(int* __restrict__ counts, int* __restrict__ fill) {
  int i = threadIdx.x;
  if (i < N_EXP) { counts[i] = 0; fill[i] = 0; }
}

// rmsnorm: f32 in -> f16 out (+ optional f32 out2)
__launch_bounds__(256)
__global__ void rmsnorm_k(const float* __restrict__ x, int in_stride, int width,
                          const float* __restrict__ w, unsigned short* __restrict__ out,
                          float* __restrict__ out2, int out_stride) {
  int row = blockIdx.x;
  const float* xr = x + (size_t)row * in_stride;
  float ss = 0.f;
  for (int i = threadIdx.x; i < width; i += 256) { float v = xr[i]; ss += v * v; }
  #pragma unroll
  for (int off = 32; off; off >>= 1) ss += __shfl_down(ss, off, 64);
  __shared__ float red[4];
  if ((threadIdx.x & 63) == 0) red[threadIdx.x >> 6] = ss;
  __syncthreads();
  if (threadIdx.x == 0) {
    float tot = red[0] + red[1] + red[2] + red[3];
    red[0] = rsqrtf(tot / (float)width + 1e-6f);
  }
  __syncthreads();
  float scale = red[0];
  for (int i = threadIdx.x; i < width; i += 256) {
    float v = xr[i] * scale * w[i];
    out[(size_t)row * out_stride + i] = f2h(v);
    if (out2) out2[(size_t)row * out_stride + i] = v;
  }
}

// ---------------- MFMA f16 TN GEMM: C[M][N] = A[M][K] @ B^T[N][K] (+R) ----------------
// grid: (N/64, M/64), block 256; global_load_lds staging, swizzled-via-source
template <int RES, int OUTH>
__launch_bounds__(256)
__global__ void gemm_bt_k(const unsigned short* __restrict__ A,
                          const unsigned short* __restrict__ B,
                          const float* __restrict__ R, void* __restrict__ Cout,
                          int N, int K) {
  const int n0 = blockIdx.x * 64;
  const int m0 = blockIdx.y * 64;
  __shared__ __align__(16) unsigned short As[64 * 64];
  __shared__ __align__(16) unsigned short Bs[64 * 64];
  const int tid = threadIdx.x;
  const int lane = tid & 63, wave = tid >> 6;
  const int quad = lane >> 4, lm = lane & 15;
  const int wm = (wave >> 1) * 32, wn = (wave & 1) * 32;
  f32x4 acc[2][2] = {};
  // staging geometry: wave covers rows wave*16..+15, two 1KB bursts (8 rows each)
  const int r0 = wave * 16 + (lane >> 3), r1 = r0 + 8;
  const int c0 = ((lane & 7) ^ smask(r0)) * 8;
  const int c1 = ((lane & 7) ^ smask(r1)) * 8;
  const unsigned short* A0 = A + (size_t)(m0 + r0) * K + c0;
  const unsigned short* A1 = A + (size_t)(m0 + r1) * K + c1;
  const unsigned short* B0 = B + (size_t)(n0 + r0) * K + c0;
  const unsigned short* B1 = B + (size_t)(n0 + r1) * K + c1;
  unsigned short* lA0 = &As[(size_t)(wave * 16) * 64];
  unsigned short* lA1 = &As[(size_t)(wave * 16 + 8) * 64];
  unsigned short* lB0 = &Bs[(size_t)(wave * 16) * 64];
  unsigned short* lB1 = &Bs[(size_t)(wave * 16 + 8) * 64];
  for (int k0 = 0; k0 < K; k0 += 64) {
    __syncthreads();
    gl16(A0 + k0, lA0);
    gl16(A1 + k0, lA1);
    gl16(B0 + k0, lB0);
    gl16(B1 + k0, lB1);
    __syncthreads();
    #pragma unroll
    for (int ks = 0; ks < 2; ks++) {
      f16x8 af0 = *(const f16x8*)&As[swz(wm + lm, ks * 32 + quad * 8)];
      f16x8 af1 = *(const f16x8*)&As[swz(wm + 16 + lm, ks * 32 + quad * 8)];
      f16x8 bf0 = *(const f16x8*)&Bs[swz(wn + lm, ks * 32 + quad * 8)];
      f16x8 bf1 = *(const f16x8*)&Bs[swz(wn + 16 + lm, ks * 32 + quad * 8)];
      acc[0][0] = __builtin_amdgcn_mfma_f32_16x16x32_f16(af0, bf0, acc[0][0], 0, 0, 0);
      acc[0][1] = __builtin_amdgcn_mfma_f32_16x16x32_f16(af0, bf1, acc[0][1], 0, 0, 0);
      acc[1][0] = __builtin_amdgcn_mfma_f32_16x16x32_f16(af1, bf0, acc[1][0], 0, 0, 0);
      acc[1][1] = __builtin_amdgcn_mfma_f32_16x16x32_f16(af1, bf1, acc[1][1], 0, 0, 0);
    }
  }
  #pragma unroll
  for (int i = 0; i < 2; i++)
    #pragma unroll
    for (int j = 0; j < 2; j++) {
      int row = m0 + wm + i * 16 + quad * 4;
      int col = n0 + wn + j * 16 + lm;
      #pragma unroll
      for (int r = 0; r < 4; r++) {
        float v = acc[i][j][r];
        if (RES) v += R[(size_t)(row + r) * N + col];
        if (OUTH) ((unsigned short*)Cout)[(size_t)(row + r) * N + col] = f2h(v);
        else ((float*)Cout)[(size_t)(row + r) * N + col] = v;
      }
    }
}

// ---------------- MoE up: h = silu(A@w1^T)*(A@w3^T), gathered token rows ----------------
// grid: (INTER/64, mtiles, E); global_load_lds staging
__launch_bounds__(256)
__global__ void moe_up_k(const unsigned short* __restrict__ xfb,
                         const unsigned short* __restrict__ w1t,
                         const unsigned short* __restrict__ w3t,
                         unsigned short* __restrict__ hout,
                         const int* __restrict__ perm, const int* __restrict__ offs,
                         int Mfull) {
  const int e = blockIdx.z;
  int base = 0, count = Mfull;
  if (offs) { base = offs[e]; count = offs[e + 1] - base; }
  const int m0 = blockIdx.y * 64;
  if (m0 >= count) return;
  const int n0 = blockIdx.x * 64;
  const unsigned short* W1 = w1t + (size_t)e * (INTER * DIM);
  const unsigned short* W3 = w3t + (size_t)e * (INTER * DIM);
  __shared__ __align__(16) unsigned short As[64 * 64];
  __shared__ __align__(16) unsigned short B1s[64 * 64];
  __shared__ __align__(16) unsigned short B2s[64 * 64];
  __shared__ int toks[64];
  const int tid = threadIdx.x;
  if (tid < 64) {
    int g = m0 + tid;
    toks[tid] = (g < count) ? (perm ? (perm[base + g] >> 2) : g) : -1;
  }
  __syncthreads();
  const int lane = tid & 63, wave = tid >> 6;
  const int quad = lane >> 4, lm = lane & 15;
  const int wm = (wave >> 1) * 32, wn = (wave & 1) * 32;
  f32x4 acc1[2][2] = {};
  f32x4 acc2[2][2] = {};
  const int r0 = wave * 16 + (lane >> 3), r1 = r0 + 8;
  const int c0 = ((lane & 7) ^ smask(r0)) * 8;
  const int c1 = ((lane & 7) ^ smask(r1)) * 8;
  int tk0 = toks[r0]; if (tk0 < 0) tk0 = 0;
  int tk1 = toks[r1]; if (tk1 < 0) tk1 = 0;
  const unsigned short* A0 = xfb + (size_t)tk0 * DIM + c0;
  const unsigned short* A1 = xfb + (size_t)tk1 * DIM + c1;
  const unsigned short* B10 = W1 + (size_t)(n0 + r0) * DIM + c0;
  const unsigned short* B11 = W1 + (size_t)(n0 + r1) * DIM + c1;
  const unsigned short* B20 = W3 + (size_t)(n0 + r0) * DIM + c0;
  const unsigned short* B21 = W3 + (size_t)(n0 + r1) * DIM + c1;
  unsigned short* lA0 = &As[(size_t)(wave * 16) * 64];
  unsigned short* lA1 = &As[(size_t)(wave * 16 + 8) * 64];
  unsigned short* lB10 = &B1s[(size_t)(wave * 16) * 64];
  unsigned short* lB11 = &B1s[(size_t)(wave * 16 + 8) * 64];
  unsigned short* lB20 = &B2s[(size_t)(wave * 16) * 64];
  unsigned short* lB21 = &B2s[(size_t)(wave * 16 + 8) * 64];
  for (int k0 = 0; k0 < DIM; k0 += 64) {
    __syncthreads();
    gl16(A0 + k0, lA0);
    gl16(A1 + k0, lA1);
    gl16(B10 + k0, lB10);
    gl16(B11 + k0, lB11);
    gl16(B20 + k0, lB20);
    gl16(B21 + k0, lB21);
    __syncthreads();
    #pragma unroll
    for (int ks = 0; ks < 2; ks++) {
      f16x8 af0 = *(const f16x8*)&As[swz(wm + lm, ks * 32 + quad * 8)];
      f16x8 af1 = *(const f16x8*)&As[swz(wm + 16 + lm, ks * 32 + quad * 8)];
      f16x8 b1f0 = *(const f16x8*)&B1s[swz(wn + lm, ks * 32 + quad * 8)];
      f16x8 b1f1 = *(const f16x8*)&B1s[swz(wn + 16 + lm, ks * 32 + quad * 8)];
      f16x8 b2f0 = *(const f16x8*)&B2s[swz(wn + lm, ks * 32 + quad * 8)];
      f16x8 b2f1 = *(const f16x8*)&B2s[swz(wn + 16 + lm, ks * 32 + quad * 8)];
      acc1[0][0] = __builtin_amdgcn_mfma_f32_16x16x32_f16(af0, b1f0, acc1[0][0], 0, 0, 0);
      acc1[0][1] = __builtin_amdgcn_mfma_f32_16x16x32_f16(af0, b1f1, acc1[0][1], 0, 0, 0);
      acc1[1][0] = __builtin_amdgcn_mfma_f32_16x16x32_f16(af1, b1f0, acc1[1][0], 0, 0, 0);
      acc1[1][1] = __builtin_amdgcn_mfma_f32_16x16x32_f16(af1, b1f1, acc1[1][1], 0, 0, 0);
      acc2[0][0] = __builtin_amdgcn_mfma_f32_16x16x32_f16(af0, b2f0, acc2[0][0], 0, 0, 0);
      acc2[0][1] = __builtin_amdgcn_mfma_f32_16x16x32_f16(af0, b2f1, acc2[0][1], 0, 0, 0);
      acc2[1][0] = __builtin_amdgcn_mfma_f32_16x16x32_f16(af1, b2f0, acc2[1][0], 0, 0, 0);
      acc2[1][1] = __builtin_amdgcn_mfma_f32_16x16x32_f16(af1, b2f1, acc2[1][1], 0, 0, 0);
    }
  }
  #pragma unroll
  for (int i = 0; i < 2; i++)
    #pragma unroll
    for (int j = 0; j < 2; j++) {
      int col = n0 + wn + j * 16 + lm;
      #pragma unroll
      for (int r = 0; r < 4; r++) {
        int g = m0 + wm + i * 16 + quad * 4 + r;
        if (g < count) {
          float u = acc1[i][j][r];
          float vv = acc2[i][j][r];
          float h = (u / (1.f + __expf(-u))) * vv;
          hout[(size_t)(base + g) * INTER + col] = f2h(h);
        }
      }
    }
}

// ---------------- MoE down: dout rows (permuted order) = h @ w2^T ----------------
// grid: (DIM/64, mtiles, E); global_load_lds staging
__launch_bounds__(256)
__global__ void moe_down_k(const unsigned short* __restrict__ hbuf,
                           const unsigned short* __restrict__ w2t,
                           unsigned short* __restrict__ dout,
                           const int* __restrict__ offs, int Mfull) {
  const int e = blockIdx.z;
  int base = 0, count = Mfull;
  if (offs) { base = offs[e]; count = offs[e + 1] - base; }
  const int m0 = blockIdx.y * 64;
  if (m0 >= count) return;
  const int n0 = blockIdx.x * 64;
  const unsigned short* W2 = w2t + (size_t)e * (DIM * INTER);
  __shared__ __align__(16) unsigned short As[64 * 64];
  __shared__ __align__(16) unsigned short Bs[64 * 64];
  const int tid = threadIdx.x;
  const int lane = tid & 63, wave = tid >> 6;
  const int quad = lane >> 4, lm = lane & 15;
  const int wm = (wave >> 1) * 32, wn = (wave & 1) * 32;
  f32x4 acc[2][2] = {};
  const int r0 = wave * 16 + (lane >> 3), r1 = r0 + 8;
  const int c0 = ((lane & 7) ^ smask(r0)) * 8;
  const int c1 = ((lane & 7) ^ smask(r1)) * 8;
  int g0 = m0 + r0; if (g0 >= count) g0 = 0;
  int g1 = m0 + r1; if (g1 >= count) g1 = 0;
  const unsigned short* A0 = hbuf + (size_t)(base + g0) * INTER + c0;
  const unsigned short* A1 = hbuf + (size_t)(base + g1) * INTER + c1;
  const unsigned short* B0 = W2 + (size_t)(n0 + r0) * INTER + c0;
  const unsigned short* B1 = W2 + (size_t)(n0 + r1) * INTER + c1;
  unsigned short* lA0 = &As[(size_t)(wave * 16) * 64];
  unsigned short* lA1 = &As[(size_t)(wave * 16 + 8) * 64];
  unsigned short* lB0 = &Bs[(size_t)(wave * 16) * 64];
  unsigned short* lB1 = &Bs[(size_t)(wave * 16 + 8) * 64];
  for (int k0 = 0; k0 < INTER; k0 += 64) {
    __syncthreads();
    gl16(A0 + k0, lA0);
    gl16(A1 + k0, lA1);
    gl16(B0 + k0, lB0);
    gl16(B1 + k0, lB1);
    __syncthreads();
    #pragma unroll
    for (int ks = 0; ks < 2; ks++) {
      f16x8 af0 = *(const f16x8*)&As[swz(wm + lm, ks * 32 + quad * 8)];
      f16x8 af1 = *(const f16x8*)&As[swz(wm + 16 + lm, ks * 32 + quad * 8)];
      f16x8 bf0 = *(const f16x8*)&Bs[swz(wn + lm, ks * 32 + quad * 8)];
      f16x8 bf1 = *(const f16x8*)&Bs[swz(wn + 16 + lm, ks * 32 + quad * 8)];
      acc[0][0] = __builtin_amdgcn_mfma_f32_16x16x32_f16(af0, bf0, acc[0][0], 0, 0, 0);
      acc[0][1] = __builtin_amdgcn_mfma_f32_16x16x32_f16(af0, bf1, acc[0][1], 0, 0, 0);
      acc[1][0] = __builtin_amdgcn_mfma_f32_16x16x32_f16(af1, bf0, acc[1][0], 0, 0, 0);
      acc[1][1] = __builtin_amdgcn_mfma_f32_16x16x32_f16(af1, bf1, acc[1][1], 0, 0, 0);
    }
  }
  #pragma unroll
  for (int i = 0; i < 2; i++)
    #pragma unroll
    for (int j = 0; j < 2; j++) {
      int col = n0 + wn + j * 16 + lm;
      #pragma unroll
      for (int r = 0; r < 4; r++) {
        int g = m0 + wm + i * 16 + quad * 4 + r;
        if (g < count)
          dout[(size_t)(base + g) * DIM + col] = f2h(acc[i][j][r]);
      }
    }
}

// ---------------- V transpose: vT[bh][d][s] = kvp[b*S+s][h*192+64+d] ----------------
// grid: (S_LEN/32, 128/32, 16), block 256
__launch_bounds__(256)
__global__ void vtrans_k(const unsigned short* __restrict__ kvp,
                         unsigned short* __restrict__ vT) {
  const int z = blockIdx.z, h = z & 7, b = z >> 3;
  const int s0 = blockIdx.x * 32, d0 = blockIdx.y * 32;
  __shared__ unsigned short ts[32][36];
  const int tid = threadIdx.x;
  const int r = tid >> 3, c4 = (tid & 7) * 4;
  ushort4 v = *(const ushort4*)(kvp + (size_t)(b * S_LEN + s0 + r) * KVP_W + h * 192 + 64 + d0 + c4);
  ts[r][c4] = v.x; ts[r][c4 + 1] = v.y; ts[r][c4 + 2] = v.z; ts[r][c4 + 3] = v.w;
  __syncthreads();
  ushort4 o;
  o.x = ts[c4][r]; o.y = ts[c4 + 1][r]; o.z = ts[c4 + 2][r]; o.w = ts[c4 + 3][r];
  *(ushort4*)(vT + ((size_t)z * 128 + d0 + r) * S_LEN + s0 + c4) = o;
}

// ---------------- attention, split-KV partials ----------------
// grid: (S/64 qt, 4 chunk, 16 bh), block 256 (4 waves; wave owns 16 query rows)
__launch_bounds__(256)
__global__ void attn_part_k(const unsigned short* __restrict__ q,
                            const unsigned short* __restrict__ kvp,
                            const float* __restrict__ kvb,
                            const unsigned short* __restrict__ vT,
                            float* __restrict__ opart, float* __restrict__ ml) {
  const int qt = blockIdx.x, ch = blockIdx.y, z = blockIdx.z;
  const int kt0 = ch * 4;
  if (kt0 > qt) return;
  const int h = z & 7, b = z >> 3;
  __shared__ __align__(16) _Float16 Ks[64][136];
  __shared__ __align__(16) _Float16 Vt[128][72];
  __shared__ __align__(16) _Float16 Ps[4][16][72];
  const int tid = threadIdx.x;
  const int lane = tid & 63, wave = tid >> 6;
  const int quad = lane >> 4, lm = lane & 15;
  const int qr0 = wave * 16;
  const float scale = 0.08838834764831845f;  // 128^-0.5
  const int tq = b * S_LEN + qt * 64;

  f16x8 qf[4];
  #pragma unroll
  for (int kc = 0; kc < 4; kc++)
    qf[kc] = *(const f16x8*)(q + (size_t)(tq + qr0 + lm) * 1024 + h * 128 + kc * 32 + quad * 8);

  float m_i[4], l_i[4];
  #pragma unroll
  for (int r = 0; r < 4; r++) { m_i[r] = -1e30f; l_i[r] = 0.f; }
  f32x4 o_acc[8] = {};

  const int kt_end = (kt0 + 3 < qt) ? (kt0 + 3) : qt;
  for (int kt = kt0; kt <= kt_end; ++kt) {
    const int tk = b * S_LEN + kt * 64;
    for (int i = tid; i < 64 * 8; i += 256) {
      int key = i & 63, g = i >> 6;
      *(f16x8*)&Ks[key][g * 8] =
          *(const f16x8*)(kvp + (size_t)(tk + key) * KVP_W + h * 192 + g * 8);
    }
    for (int i = tid; i < 64 * 16; i += 256) {
      int key = i & 63, g = i >> 6;
      float4 v = *(const float4*)(kvb + (size_t)(tk + key) * 320 + 256 + g * 4);
      ushort4 u;
      u.x = f2h(v.x); u.y = f2h(v.y); u.z = f2h(v.z); u.w = f2h(v.w);
      *(ushort4*)&Ks[key][64 + g * 4] = u;
    }
    for (int i = tid; i < 128 * 8; i += 256) {
      int d = i >> 3, seg = i & 7;
      *(f16x8*)&Vt[d][seg * 8] =
          *(const f16x8*)(vT + ((size_t)z * 128 + d) * S_LEN + kt * 64 + seg * 8);
    }
    __syncthreads();

    f32x4 sacc[4] = {};
    #pragma unroll
    for (int kc = 0; kc < 4; kc++) {
      #pragma unroll
      for (int jn = 0; jn < 4; jn++) {
        f16x8 bf = *(const f16x8*)&Ks[jn * 16 + lm][kc * 32 + quad * 8];
        sacc[jn] = __builtin_amdgcn_mfma_f32_16x16x32_f16(qf[kc], bf, sacc[jn], 0, 0, 0);
      }
    }
    const bool diag = (kt == qt);
    float p[4][4];
    float rowmax[4], rowsum[4];
    #pragma unroll
    for (int r = 0; r < 4; r++) rowmax[r] = -1e30f;
    #pragma unroll
    for (int jn = 0; jn < 4; jn++)
      #pragma unroll
      for (int r = 0; r < 4; r++) {
        float s = sacc[jn][r] * scale;
        if (diag && (jn * 16 + lm > qr0 + quad * 4 + r)) s = -1e30f;
        p[jn][r] = s;
        rowmax[r] = fmaxf(rowmax[r], s);
      }
    #pragma unroll
    for (int m = 1; m < 16; m <<= 1)
      #pragma unroll
      for (int r = 0; r < 4; r++)
        rowmax[r] = fmaxf(rowmax[r], __shfl_xor(rowmax[r], m, 64));
    float al[4];
    #pragma unroll
    for (int r = 0; r < 4; r++) {
      float mn = fmaxf(m_i[r], rowmax[r]);
      al[r] = __expf(m_i[r] - mn);
      m_i[r] = mn;
      rowsum[r] = 0.f;
    }
    #pragma unroll
    for (int jn = 0; jn < 4; jn++)
      #pragma unroll
      for (int r = 0; r < 4; r++) {
        float pv = __expf(p[jn][r] - m_i[r]);
        p[jn][r] = pv;
        rowsum[r] += pv;
      }
    #pragma unroll
    for (int m = 1; m < 16; m <<= 1)
      #pragma unroll
      for (int r = 0; r < 4; r++)
        rowsum[r] += __shfl_xor(rowsum[r], m, 64);
    #pragma unroll
    for (int r = 0; r < 4; r++) l_i[r] = l_i[r] * al[r] + rowsum[r];
    #pragma unroll
    for (int jn2 = 0; jn2 < 8; jn2++)
      #pragma unroll
      for (int r = 0; r < 4; r++) o_acc[jn2][r] *= al[r];
    #pragma unroll
    for (int jn = 0; jn < 4; jn++)
      #pragma unroll
      for (int r = 0; r < 4; r++)
        Ps[wave][quad * 4 + r][jn * 16 + lm] = (_Float16)p[jn][r];
    #pragma unroll
    for (int kc = 0; kc < 2; kc++) {
      f16x8 af = *(const f16x8*)&Ps[wave][lm][kc * 32 + quad * 8];
      #pragma unroll
      for (int jn2 = 0; jn2 < 8; jn2++) {
        f16x8 bf = *(const f16x8*)&Vt[jn2 * 16 + lm][kc * 32 + quad * 8];
        o_acc[jn2] = __builtin_amdgcn_mfma_f32_16x16x32_f16(af, bf, o_acc[jn2], 0, 0, 0);
      }
    }
    __syncthreads();
  }

  const size_t slot = ((size_t)z * 16 + qt) * 4 + ch;
  float* op = opart + slot * 8192;
  #pragma unroll
  for (int jn2 = 0; jn2 < 8; jn2++) {
    int col = jn2 * 16 + lm;
    #pragma unroll
    for (int r = 0; r < 4; r++) {
      int row = qr0 + quad * 4 + r;
      op[(size_t)row * 128 + col] = o_acc[jn2][r];
    }
  }
  if (lm == 0) {
    #pragma unroll
    for (int r = 0; r < 4; r++) {
      int row = qr0 + quad * 4 + r;
      ml[slot * 128 + row * 2] = m_i[r];
      ml[slot * 128 + row * 2 + 1] = l_i[r];
    }
  }
}

// ---------------- attention combine: rescale + sum partials -> atn f16 ----------------
// grid: (16 qt, 16 bh), block 256
__launch_bounds__(256)
__global__ void attn_comb_k(const float* __restrict__ opart, const float* __restrict__ ml,
                            unsigned short* __restrict__ o) {
  const int qt = blockIdx.x, z = blockIdx.y;
  const int h = z & 7, b = z >> 3;
  const int nch = (qt >> 2) + 1;
  const int tid = threadIdx.x;
  const int colg = tid & 31;            // cols colg*4 .. colg*4+3
  const int tq = b * S_LEN + qt * 64;
  const size_t slotbase = ((size_t)z * 16 + qt) * 4;
  for (int row = tid >> 5; row < 64; row += 8) {
    float mmax = -1e30f;
    #pragma unroll
    for (int c = 0; c < 4; c++)
      if (c < nch) mmax = fmaxf(mmax, ml[(slotbase + c) * 128 + row * 2]);
    float w[4];
    float lsum = 0.f;
    #pragma unroll
    for (int c = 0; c < 4; c++) {
      if (c < nch) {
        float mc = ml[(slotbase + c) * 128 + row * 2];
        float lc = ml[(slotbase + c) * 128 + row * 2 + 1];
        w[c] = __expf(mc - mmax);
        lsum += lc * w[c];
      } else w[c] = 0.f;
    }
    float inv = 1.f / lsum;
    float ax = 0.f, ay = 0.f, az = 0.f, aw = 0.f;
    #pragma unroll
    for (int c = 0; c < 4; c++) {
      if (c < nch) {
        const float* op = opart + (slotbase + c) * 8192 + (size_t)row * 128 + colg * 4;
        float4 v = *(const float4*)op;
        ax += w[c] * v.x; ay += w[c] * v.y; az += w[c] * v.z; aw += w[c] * v.w;
      }
    }
    ushort4 u;
    u.x = f2h(ax * inv); u.y = f2h(ay * inv);
    u.z = f2h(az * inv); u.w = f2h(aw * inv);
    *(ushort4*)(o + (size_t)(tq + row) * 1024 + h * 128 + colg * 4) = u;
  }
}

// ---------------- gate scores: logits[T][32] = xf32 @ gw^T, f32 ----------------
// grid: T/32 blocks, 256 threads
__launch_bounds__(256)
__global__ void scores_k(const float* __restrict__ xf, const float* __restrict__ gw,
                         float* __restrict__ sc) {
  __shared__ float xls[32][129];
  __shared__ float gls[32][129];
  const int t0 = blockIdx.x * 32;
  const int tid = threadIdx.x;
  const int lr = tid >> 3, lc = tid & 7;   // loader: row, col-group
  const int e = tid & 31, tg = tid >> 5;   // compute: expert, token-group
  float acc[4] = {};
  for (int k0 = 0; k0 < DIM; k0 += 128) {
    __syncthreads();
    #pragma unroll
    for (int it = 0; it < 4; it++) {
      int col = lc * 4 + it * 32;
      *(float4*)&xls[lr][col] = *(const float4*)(xf + (size_t)(t0 + lr) * DIM + k0 + col);
      *(float4*)&gls[lr][col] = *(const float4*)(gw + (size_t)lr * DIM + k0 + col);
    }
    __syncthreads();
    for (int d = 0; d < 128; d++) {
      float g = gls[e][d];
      #pragma unroll
      for (int j = 0; j < 4; j++)
        acc[j] += xls[tg * 4 + j][d] * g;
    }
  }
  #pragma unroll
  for (int j = 0; j < 4; j++)
    sc[(size_t)(t0 + tg * 4 + j) * N_EXP + e] = acc[j];
}

// ---------------- routing: one thread per token, bitmask selection ----------------
// grid: T/64 blocks, 64 threads
__launch_bounds__(64)
__global__ void route_k(const float* __restrict__ sc, const float* __restrict__ gb,
                        float* __restrict__ tw, int* __restrict__ tidx,
                        int* __restrict__ counts) {
  int t = blockIdx.x * 64 + threadIdx.x;
  if (t >= T_TOK) return;
  float orig[N_EXP], sb[N_EXP];
  #pragma unroll
  for (int i = 0; i < N_EXP; i++) {
    float s = 1.f / (1.f + __expf(-sc[(size_t)t * N_EXP + i]));
    orig[i] = s;
    sb[i] = s + gb[i];
  }
  float gsc[8];
  #pragma unroll
  for (int g = 0; g < 8; g++) {
    float m1 = -1e30f, m2 = -1e30f;
    #pragma unroll
    for (int j = 0; j < 4; j++) {
      float v = sb[g * 4 + j];
      if (v > m1) { m2 = m1; m1 = v; } else if (v > m2) m2 = v;
    }
    gsc[g] = m1 + m2;
  }
  unsigned gok = 0;
  #pragma unroll
  for (int it = 0; it < 4; it++) {
    int best = 0; float bv = -1e30f;
    #pragma unroll
    for (int g = 0; g < 8; g++)
      if (!((gok >> g) & 1u) && gsc[g] >= bv) { bv = gsc[g]; best = g; }
    gok |= 1u << best;
  }
  unsigned emask = 0;
  #pragma unroll
  for (int g = 0; g < 8; g++)
    if ((gok >> g) & 1u) emask |= 0xFu << (g * 4);
  unsigned taken = 0;
  int idx[TOPK]; float ow[TOPK]; float wsum = 0.f;
  #pragma unroll
  for (int k = 0; k < TOPK; k++) {
    int best = 0; float bv = -1e30f, bo = 0.f;
    #pragma unroll
    for (int i = 0; i < N_EXP; i++)
      if (((emask >> i) & 1u) && !((taken >> i) & 1u) && sb[i] >= bv) {
        bv = sb[i]; best = i; bo = orig[i];
      }
    taken |= 1u << best;
    idx[k] = best; ow[k] = bo; wsum += bo;
  }
  float inv = 1.f / (wsum + 1e-20f);
  #pragma unroll
  for (int k = 0; k < TOPK; k++) {
    tidx[t * TOPK + k] = idx[k];
    tw[t * TOPK + k] = ow[k] * inv;
    atomicAdd(&counts[idx[k]], 1);
  }
}

__global__ void scan_k(const int* __restrict__ counts, int* __restrict__ offs) {
  if (threadIdx.x == 0 && blockIdx.x == 0) {
    int acc = 0;
    for (int e = 0; e < N_EXP; e++) { offs[e] = acc; acc += counts[e]; }
    offs[N_EXP] = acc;
  }
}

__launch_bounds__(256)
__global__ void scatter_k(const int* __restrict__ tidx, const int* __restrict__ offs,
                          int* __restrict__ fill, int* __restrict__ perm,
                          int* __restrict__ posOf) {
  int t = blockIdx.x * 256 + threadIdx.x;
  if (t >= T_TOK) return;
  for (int j = 0; j < TOPK; j++) {
    int e = tidx[t * TOPK + j];
    int pos = atomicAdd(&fill[e], 1);
    int p = offs[e] + pos;
    perm[p] = t * TOPK + j;
    posOf[t * TOPK + j] = p;
  }
}

// ---------------- final combine ----------------
__launch_bounds__(256)
__global__ void final_gather_k(const float* __restrict__ x1,
                               const unsigned short* __restrict__ dbuf,
                               const unsigned short* __restrict__ sdbuf,
                               const int* __restrict__ posOf,
                               const float* __restrict__ tw,
                               float* __restrict__ out) {
  int t = blockIdx.x;
  int c0 = threadIdx.x * 4;
  int p0 = posOf[t * 4 + 0], p1 = posOf[t * 4 + 1];
  int p2 = posOf[t * 4 + 2], p3 = posOf[t * 4 + 3];
  float w0 = tw[t * 4 + 0], w1 = tw[t * 4 + 1];
  float w2 = tw[t * 4 + 2], w3 = tw[t * 4 + 3];
  size_t tb = (size_t)t * DIM;
  #pragma unroll
  for (int i = 0; i < 4; i++) {
    int c = c0 + i;
    float v = x1[tb + c] + h2f(sdbuf[tb + c])
            + w0 * h2f(dbuf[(size_t)p0 * DIM + c])
            + w1 * h2f(dbuf[(size_t)p1 * DIM + c])
            + w2 * h2f(dbuf[(size_t)p2 * DIM + c])
            + w3 * h2f(dbuf[(size_t)p3 * DIM + c]);
    out[tb + c] = v;
  }
}

// ---------------- host launch ----------------
extern "C" void kernel_launch(void* const* d_in, const int* in_sizes, int n_in,
                              void* d_out, int out_size, void* d_ws, size_t ws_size,
                              hipStream_t stream) {
  const float* x        = (const float*)d_in[0];
  const float* norm_attn= (const float*)d_in[1];
  const float* wq       = (const float*)d_in[2];
  const float* wkv_a    = (const float*)d_in[3];
  const float* kv_norm_w= (const float*)d_in[4];
  const float* wkv_b    = (const float*)d_in[5];
  const float* wo       = (const float*)d_in[6];
  const float* norm_moe = (const float*)d_in[7];
  const float* gate_w   = (const float*)d_in[8];
  const float* gate_b   = (const float*)d_in[9];
  const float* ew1      = (const float*)d_in[10];
  const float* ew2      = (const float*)d_in[11];
  const float* ew3      = (const float*)d_in[12];
  const float* sw1      = (const float*)d_in[13];
  const float* sw2      = (const float*)d_in[14];
  const float* sw3      = (const float*)d_in[15];
  float* out = (float*)d_out;

  char* wp = (char*)d_ws;
  auto alloc = [&](size_t bytes) -> char* {
    char* r = wp;
    wp += (bytes + 255) & ~(size_t)255;
    return r;
  };
  typedef unsigned short us;
  us* wqT   = (us*)alloc(1048576 * 2);
  us* wkvaT = (us*)alloc(327680 * 2);
  us* wkvbT = (us*)alloc(393216 * 2);
  us* woT   = (us*)alloc(1048576 * 2);
  us* ew1T  = (us*)alloc((size_t)16777216 * 2);
  us* ew3T  = (us*)alloc((size_t)16777216 * 2);
  us* ew2T  = (us*)alloc((size_t)16777216 * 2);
  us* sw1T  = (us*)alloc(524288 * 2);
  us* sw3T  = (us*)alloc(524288 * 2);
  us* sw2T  = (us*)alloc(524288 * 2);
  us* xb    = (us*)alloc(2097152 * 2);   // xn, later xfb
  us* cn    = (us*)alloc(524288 * 2);
  us* atn   = (us*)alloc(2097152 * 2);
  us* dbuf  = (us*)alloc((size_t)8388608 * 2);
  us* qb    = (us*)alloc(2097152 * 4);    // f16 q; later sdbuf aliases
  float* kvb  = (float*)alloc(655360 * 4);
  us* kvp   = (us*)alloc(3145728 * 4);    // f16 kvp; later hbuf+hs alias
  float* x1   = (float*)alloc(2097152 * 4);
  float* xf32 = (float*)alloc(2097152 * 4);
  float* scb  = (float*)alloc(65536 * 4);
  float* twb  = (float*)alloc(8192 * 4);
  int* tidx   = (int*)alloc(8192 * 4);
  int* perm   = (int*)alloc(8192 * 4);
  int* posOf  = (int*)alloc(8192 * 4);
  int* counts = (int*)alloc(64 * 4);
  int* offs   = (int*)alloc(64 * 4);
  int* fill   = (int*)alloc(64 * 4);
  us* vT     = (us*)alloc((size_t)2 * 8 * 128 * 1024 * 2);   // 4 MB
  float* mlb = (float*)alloc((size_t)1024 * 128 * 4);        // 512 KB
  us* sdbuf = qb;
  us* hbuf  = kvp;
  us* hs    = hbuf + (size_t)8192 * 512;
  // attention partials (32 MB) alias ew1T: written/read before ew1 tcvt runs
  float* opart = (float*)ew1T;

  // small weight transposes needed for MLA path
  tcvt_k<<<dim3(32, 32, 1), 256, 0, stream>>>(wq, wqT, 1024, 1024);
  tcvt_k<<<dim3(10, 32, 1), 256, 0, stream>>>(wkv_a, wkvaT, 1024, 320);
  tcvt_k<<<dim3(48, 8, 1), 256, 0, stream>>>(wkv_b, wkvbT, 256, 1536);
  tcvt_k<<<dim3(32, 32, 1), 256, 0, stream>>>(wo, woT, 1024, 1024);

  // ---- MLA ----
  rmsnorm_k<<<T_TOK, 256, 0, stream>>>(x, DIM, DIM, norm_attn, xb, nullptr, DIM);
  gemm_bt_k<0, 1><<<dim3(16, 32), 256, 0, stream>>>(xb, wqT, nullptr, qb, 1024, 1024);
  gemm_bt_k<0, 0><<<dim3(5, 32), 256, 0, stream>>>(xb, wkvaT, nullptr, kvb, 320, 1024);
  rmsnorm_k<<<T_TOK, 256, 0, stream>>>(kvb, 320, KV_LORA, kv_norm_w, cn, nullptr, KV_LORA);
  gemm_bt_k<0, 1><<<dim3(24, 32), 256, 0, stream>>>(cn, wkvbT, nullptr, kvp, 1536, 256);
  vtrans_k<<<dim3(32, 4, 16), 256, 0, stream>>>(kvp, vT);
  attn_part_k<<<dim3(16, 4, 16), 256, 0, stream>>>(qb, kvp, kvb, vT, opart, mlb);
  attn_comb_k<<<dim3(16, 16), 256, 0, stream>>>(opart, mlb, atn);
  gemm_bt_k<1, 0><<<dim3(16, 32), 256, 0, stream>>>(atn, woT, x, x1, 1024, 1024);

  // expert / shared weight conversion (after attention: opart aliased ew1T)
  tcvt_k<<<dim3(16, 32, 32), 256, 0, stream>>>(ew1, ew1T, 1024, 512);
  tcvt_k<<<dim3(16, 32, 32), 256, 0, stream>>>(ew3, ew3T, 1024, 512);
  tcvt_k<<<dim3(32, 16, 32), 256, 0, stream>>>(ew2, ew2T, 512, 1024);
  tcvt_k<<<dim3(16, 32, 1), 256, 0, stream>>>(sw1, sw1T, 1024, 512);
  tcvt_k<<<dim3(16, 32, 1), 256, 0, stream>>>(sw3, sw3T, 1024, 512);
  tcvt_k<<<dim3(32, 16, 1), 256, 0, stream>>>(sw2, sw2T, 512, 1024);

  // ---- MoE ----
  rmsnorm_k<<<T_TOK, 256, 0, stream>>>(x1, DIM, DIM, norm_moe, xb, xf32, DIM);
  zero_counters_k<<<1, 64, 0, stream>>>(counts, fill);
  scores_k<<<T_TOK / 32, 256, 0, stream>>>(xf32, gate_w, scb);
  route_k<<<T_TOK / 64, 64, 0, stream>>>(scb, gate_b, twb, tidx, counts);
  scan_k<<<1, 1, 0, stream>>>(counts, offs);
  scatter_k<<<(T_TOK + 255) / 256, 256, 0, stream>>>(tidx, offs, fill, perm, posOf);
  moe_up_k<<<dim3(8, 32, 32), 256, 0, stream>>>(xb, ew1T, ew3T, hbuf, perm, offs, 0);
  moe_down_k<<<dim3(16, 32, 32), 256, 0, stream>>>(hbuf, ew2T, dbuf, offs, 0);
  moe_up_k<<<dim3(8, 32, 1), 256, 0, stream>>>(xb, sw1T, sw3T, hs, nullptr, nullptr, T_TOK);
  moe_down_k<<<dim3(16, 32, 1), 256, 0, stream>>>(hs, sw2T, sdbuf, nullptr, T_TOK);

  final_gather_k<<<T_TOK, 256, 0, stream>>>(x1, dbuf, sdbuf, posOf, twb, out);
}

// Round 9
// 531.136 us; speedup vs baseline: 1.0373x; 1.0373x over previous
//
#include <hip/hip_runtime.h>
#include <hip/hip_bf16.h>

#define T_TOK 2048
#define DIM 1024
#define HEADS 8
#define QK_HD 128
#define V_HD 128
#define NOPE 64
#define ROPE 64
#define KV_LORA 256
#define N_EXP 32
#define TOPK 4
#define INTER 512
#define S_LEN 1024
#define KVP_W (HEADS * (NOPE + V_HD))   // 1536

typedef __attribute__((ext_vector_type(8))) _Float16 f16x8;
typedef __attribute__((ext_vector_type(4))) float f32x4;

__device__ inline unsigned short f2h(float f) {
  union { _Float16 h; unsigned short u; } c;
  c.h = (_Float16)f;
  return c.u;
}
__device__ inline float h2f(unsigned short u) {
  union { _Float16 h; unsigned short u; } c;
  c.u = u;
  return (float)c.h;
}

// XOR swizzle mask for a [64][64] f16 LDS tile (16B-chunk granular). Verified R5/R8.
__device__ inline int smask(int row) { return (row & 7) ^ ((row & 3) << 1); }
__device__ inline int swz(int row, int col) {
  return row * 64 + (col ^ (smask(row) << 3));
}

// async global->LDS, 16B per lane. LDS dest is wave-uniform base + lane*16 (HW);
// global src is per-lane. Swizzled layout achieved by pre-swizzling the source col.
__device__ inline void gl16(const void* g, void* l) {
  __builtin_amdgcn_global_load_lds(
      (const __attribute__((address_space(1))) void*)g,
      (__attribute__((address_space(3))) void*)l, 16, 0, 0);
}

// ---------------- transpose + f32->f16 convert: dst[n][k] = src[k][n] ----------------
// grid: (N/32, K/32, E), block 256
__launch_bounds__(256)
__global__ void tcvt_k(const float* __restrict__ src, unsigned short* __restrict__ dst,
                       int K, int N) {
  int e = blockIdx.z;
  src += (size_t)e * K * N;
  dst += (size_t)e * K * N;
  int n0 = blockIdx.x * 32, k0 = blockIdx.y * 32;
  __shared__ float ts[32][33];
  int tid = threadIdx.x;
  int r = tid >> 3, c4 = (tid & 7) * 4;
  float4 v = *(const float4*)(src + (size_t)(k0 + r) * N + n0 + c4);
  ts[r][c4] = v.x; ts[r][c4 + 1] = v.y; ts[r][c4 + 2] = v.z; ts[r][c4 + 3] = v.w;
  __syncthreads();
  ushort4 o;
  o.x = f2h(ts[c4][r]);
  o.y = f2h(ts[c4 + 1][r]);
  o.z = f2h(ts[c4 + 2][r]);
  o.w = f2h(ts[c4 + 3][r]);
  *(ushort4*)(dst + (size_t)(n0 + r) * K + k0 + c4) = o;
}

__launch_bounds__(64)
__global__ void zero_counters_k(int* __restrict__ counts, int* __restrict__ fill) {
  int i = threadIdx.x;
  if (i < N_EXP) { counts[i] = 0; fill[i] = 0; }
}

// rmsnorm: f32 in -> f16 out (+ optional f32 out2)
__launch_bounds__(256)
__global__ void rmsnorm_k(const float* __restrict__ x, int in_stride, int width,
                          const float* __restrict__ w, unsigned short* __restrict__ out,
                          float* __restrict__ out2, int out_stride) {
  int row = blockIdx.x;
  const float* xr = x + (size_t)row * in_stride;
  float ss = 0.f;
  for (int i = threadIdx.x; i < width; i += 256) { float v = xr[i]; ss += v * v; }
  #pragma unroll
  for (int off = 32; off; off >>= 1) ss += __shfl_down(ss, off, 64);
  __shared__ float red[4];
  if ((threadIdx.x & 63) == 0) red[threadIdx.x >> 6] = ss;
  __syncthreads();
  if (threadIdx.x == 0) {
    float tot = red[0] + red[1] + red[2] + red[3];
    red[0] = rsqrtf(tot / (float)width + 1e-6f);
  }
  __syncthreads();
  float scale = red[0];
  for (int i = threadIdx.x; i < width; i += 256) {
    float v = xr[i] * scale * w[i];
    out[(size_t)row * out_stride + i] = f2h(v);
    if (out2) out2[(size_t)row * out_stride + i] = v;
  }
}

// ---------------- MFMA f16 TN GEMM: C[M][N] = A[M][K] @ B^T[N][K] (+R) ----------------
// grid: (N/64, M/64), block 256; reg-staged depth-1 prefetch (best at low TLP); swizzled LDS
template <int RES, int OUTH>
__launch_bounds__(256)
__global__ void gemm_bt_k(const unsigned short* __restrict__ A,
                          const unsigned short* __restrict__ B,
                          const float* __restrict__ R, void* __restrict__ Cout,
                          int N, int K) {
  const int n0 = blockIdx.x * 64;
  const int m0 = blockIdx.y * 64;
  __shared__ __align__(16) unsigned short As[64 * 64];
  __shared__ __align__(16) unsigned short Bs[64 * 64];
  const int tid = threadIdx.x;
  const int lane = tid & 63, wave = tid >> 6;
  const int quad = lane >> 4, lm = lane & 15;
  const int wm = (wave >> 1) * 32, wn = (wave & 1) * 32;
  f32x4 acc[2][2] = {};
  const int sr = tid >> 2, sc = tid & 3;
  const unsigned short* Ap = A + (size_t)(m0 + sr) * K;
  const unsigned short* Bp = B + (size_t)(n0 + sr) * K;
  f16x8 a0 = *(const f16x8*)(Ap + sc * 8);
  f16x8 a1 = *(const f16x8*)(Ap + sc * 8 + 32);
  f16x8 b0 = *(const f16x8*)(Bp + sc * 8);
  f16x8 b1 = *(const f16x8*)(Bp + sc * 8 + 32);
  for (int k0 = 0; k0 < K; k0 += 64) {
    __syncthreads();
    *(f16x8*)&As[swz(sr, sc * 8)] = a0;
    *(f16x8*)&As[swz(sr, sc * 8 + 32)] = a1;
    *(f16x8*)&Bs[swz(sr, sc * 8)] = b0;
    *(f16x8*)&Bs[swz(sr, sc * 8 + 32)] = b1;
    __syncthreads();
    const int kn = k0 + 64;
    if (kn < K) {
      a0 = *(const f16x8*)(Ap + kn + sc * 8);
      a1 = *(const f16x8*)(Ap + kn + sc * 8 + 32);
      b0 = *(const f16x8*)(Bp + kn + sc * 8);
      b1 = *(const f16x8*)(Bp + kn + sc * 8 + 32);
    }
    #pragma unroll
    for (int ks = 0; ks < 2; ks++) {
      f16x8 af0 = *(const f16x8*)&As[swz(wm + lm, ks * 32 + quad * 8)];
      f16x8 af1 = *(const f16x8*)&As[swz(wm + 16 + lm, ks * 32 + quad * 8)];
      f16x8 bf0 = *(const f16x8*)&Bs[swz(wn + lm, ks * 32 + quad * 8)];
      f16x8 bf1 = *(const f16x8*)&Bs[swz(wn + 16 + lm, ks * 32 + quad * 8)];
      acc[0][0] = __builtin_amdgcn_mfma_f32_16x16x32_f16(af0, bf0, acc[0][0], 0, 0, 0);
      acc[0][1] = __builtin_amdgcn_mfma_f32_16x16x32_f16(af0, bf1, acc[0][1], 0, 0, 0);
      acc[1][0] = __builtin_amdgcn_mfma_f32_16x16x32_f16(af1, bf0, acc[1][0], 0, 0, 0);
      acc[1][1] = __builtin_amdgcn_mfma_f32_16x16x32_f16(af1, bf1, acc[1][1], 0, 0, 0);
    }
  }
  #pragma unroll
  for (int i = 0; i < 2; i++)
    #pragma unroll
    for (int j = 0; j < 2; j++) {
      int row = m0 + wm + i * 16 + quad * 4;
      int col = n0 + wn + j * 16 + lm;
      #pragma unroll
      for (int r = 0; r < 4; r++) {
        float v = acc[i][j][r];
        if (RES) v += R[(size_t)(row + r) * N + col];
        if (OUTH) ((unsigned short*)Cout)[(size_t)(row + r) * N + col] = f2h(v);
        else ((float*)Cout)[(size_t)(row + r) * N + col] = v;
      }
    }
}

// ---------------- MoE up (fused: routed e<N_EXP, shared e==N_EXP) ----------------
// grid: (INTER/64, mtiles, N_EXP+1); global_load_lds staging; swizzled LDS
__launch_bounds__(256)
__global__ void moe_up_k(const unsigned short* __restrict__ xfb,
                         const unsigned short* __restrict__ w1t,
                         const unsigned short* __restrict__ w3t,
                         const unsigned short* __restrict__ sw1t,
                         const unsigned short* __restrict__ sw3t,
                         unsigned short* __restrict__ hout,
                         unsigned short* __restrict__ hs,
                         const int* __restrict__ perm, const int* __restrict__ offs) {
  const int e = blockIdx.z;
  const bool se = (e == N_EXP);
  const int base = se ? 0 : offs[e];
  const int count = se ? T_TOK : (offs[e + 1] - base);
  const int m0 = blockIdx.y * 64;
  if (m0 >= count) return;
  const int n0 = blockIdx.x * 64;
  const unsigned short* W1 = se ? sw1t : (w1t + (size_t)e * (INTER * DIM));
  const unsigned short* W3 = se ? sw3t : (w3t + (size_t)e * (INTER * DIM));
  unsigned short* H = se ? hs : hout;
  __shared__ __align__(16) unsigned short As[64 * 64];
  __shared__ __align__(16) unsigned short B1s[64 * 64];
  __shared__ __align__(16) unsigned short B2s[64 * 64];
  __shared__ int toks[64];
  const int tid = threadIdx.x;
  if (tid < 64) {
    int g = m0 + tid;
    toks[tid] = (g < count) ? (se ? g : (perm[base + g] >> 2)) : -1;
  }
  __syncthreads();
  const int lane = tid & 63, wave = tid >> 6;
  const int quad = lane >> 4, lm = lane & 15;
  const int wm = (wave >> 1) * 32, wn = (wave & 1) * 32;
  f32x4 acc1[2][2] = {};
  f32x4 acc2[2][2] = {};
  const int r0 = wave * 16 + (lane >> 3), r1 = r0 + 8;
  const int c0 = ((lane & 7) ^ smask(r0)) * 8;
  const int c1 = ((lane & 7) ^ smask(r1)) * 8;
  int tk0 = toks[r0]; if (tk0 < 0) tk0 = 0;
  int tk1 = toks[r1]; if (tk1 < 0) tk1 = 0;
  const unsigned short* A0 = xfb + (size_t)tk0 * DIM + c0;
  const unsigned short* A1 = xfb + (size_t)tk1 * DIM + c1;
  const unsigned short* B10 = W1 + (size_t)(n0 + r0) * DIM + c0;
  const unsigned short* B11 = W1 + (size_t)(n0 + r1) * DIM + c1;
  const unsigned short* B20 = W3 + (size_t)(n0 + r0) * DIM + c0;
  const unsigned short* B21 = W3 + (size_t)(n0 + r1) * DIM + c1;
  unsigned short* lA0 = &As[(size_t)(wave * 16) * 64];
  unsigned short* lA1 = &As[(size_t)(wave * 16 + 8) * 64];
  unsigned short* lB10 = &B1s[(size_t)(wave * 16) * 64];
  unsigned short* lB11 = &B1s[(size_t)(wave * 16 + 8) * 64];
  unsigned short* lB20 = &B2s[(size_t)(wave * 16) * 64];
  unsigned short* lB21 = &B2s[(size_t)(wave * 16 + 8) * 64];
  for (int k0 = 0; k0 < DIM; k0 += 64) {
    __syncthreads();
    gl16(A0 + k0, lA0);
    gl16(A1 + k0, lA1);
    gl16(B10 + k0, lB10);
    gl16(B11 + k0, lB11);
    gl16(B20 + k0, lB20);
    gl16(B21 + k0, lB21);
    __syncthreads();
    #pragma unroll
    for (int ks = 0; ks < 2; ks++) {
      f16x8 af0 = *(const f16x8*)&As[swz(wm + lm, ks * 32 + quad * 8)];
      f16x8 af1 = *(const f16x8*)&As[swz(wm + 16 + lm, ks * 32 + quad * 8)];
      f16x8 b1f0 = *(const f16x8*)&B1s[swz(wn + lm, ks * 32 + quad * 8)];
      f16x8 b1f1 = *(const f16x8*)&B1s[swz(wn + 16 + lm, ks * 32 + quad * 8)];
      f16x8 b2f0 = *(const f16x8*)&B2s[swz(wn + lm, ks * 32 + quad * 8)];
      f16x8 b2f1 = *(const f16x8*)&B2s[swz(wn + 16 + lm, ks * 32 + quad * 8)];
      acc1[0][0] = __builtin_amdgcn_mfma_f32_16x16x32_f16(af0, b1f0, acc1[0][0], 0, 0, 0);
      acc1[0][1] = __builtin_amdgcn_mfma_f32_16x16x32_f16(af0, b1f1, acc1[0][1], 0, 0, 0);
      acc1[1][0] = __builtin_amdgcn_mfma_f32_16x16x32_f16(af1, b1f0, acc1[1][0], 0, 0, 0);
      acc1[1][1] = __builtin_amdgcn_mfma_f32_16x16x32_f16(af1, b1f1, acc1[1][1], 0, 0, 0);
      acc2[0][0] = __builtin_amdgcn_mfma_f32_16x16x32_f16(af0, b2f0, acc2[0][0], 0, 0, 0);
      acc2[0][1] = __builtin_amdgcn_mfma_f32_16x16x32_f16(af0, b2f1, acc2[0][1], 0, 0, 0);
      acc2[1][0] = __builtin_amdgcn_mfma_f32_16x16x32_f16(af1, b2f0, acc2[1][0], 0, 0, 0);
      acc2[1][1] = __builtin_amdgcn_mfma_f32_16x16x32_f16(af1, b2f1, acc2[1][1], 0, 0, 0);
    }
  }
  #pragma unroll
  for (int i = 0; i < 2; i++)
    #pragma unroll
    for (int j = 0; j < 2; j++) {
      int col = n0 + wn + j * 16 + lm;
      #pragma unroll
      for (int r = 0; r < 4; r++) {
        int g = m0 + wm + i * 16 + quad * 4 + r;
        if (g < count) {
          float u = acc1[i][j][r];
          float vv = acc2[i][j][r];
          float h = (u / (1.f + __expf(-u))) * vv;
          H[(size_t)(base + g) * INTER + col] = f2h(h);
        }
      }
    }
}

// ---------------- MoE down (fused: routed e<N_EXP, shared e==N_EXP) ----------------
// grid: (DIM/64, mtiles, N_EXP+1); global_load_lds staging
__launch_bounds__(256)
__global__ void moe_down_k(const unsigned short* __restrict__ hbuf,
                           const unsigned short* __restrict__ hs,
                           const unsigned short* __restrict__ w2t,
                           const unsigned short* __restrict__ sw2t,
                           unsigned short* __restrict__ dbuf,
                           unsigned short* __restrict__ sdbuf,
                           const int* __restrict__ offs) {
  const int e = blockIdx.z;
  const bool se = (e == N_EXP);
  const int base = se ? 0 : offs[e];
  const int count = se ? T_TOK : (offs[e + 1] - base);
  const int m0 = blockIdx.y * 64;
  if (m0 >= count) return;
  const int n0 = blockIdx.x * 64;
  const unsigned short* W2 = se ? sw2t : (w2t + (size_t)e * (DIM * INTER));
  const unsigned short* Hsrc = se ? hs : hbuf;
  unsigned short* Dout = se ? sdbuf : dbuf;
  __shared__ __align__(16) unsigned short As[64 * 64];
  __shared__ __align__(16) unsigned short Bs[64 * 64];
  const int tid = threadIdx.x;
  const int lane = tid & 63, wave = tid >> 6;
  const int quad = lane >> 4, lm = lane & 15;
  const int wm = (wave >> 1) * 32, wn = (wave & 1) * 32;
  f32x4 acc[2][2] = {};
  const int r0 = wave * 16 + (lane >> 3), r1 = r0 + 8;
  const int c0 = ((lane & 7) ^ smask(r0)) * 8;
  const int c1 = ((lane & 7) ^ smask(r1)) * 8;
  int g0 = m0 + r0; if (g0 >= count) g0 = 0;
  int g1 = m0 + r1; if (g1 >= count) g1 = 0;
  const unsigned short* A0 = Hsrc + (size_t)(base + g0) * INTER + c0;
  const unsigned short* A1 = Hsrc + (size_t)(base + g1) * INTER + c1;
  const unsigned short* B0 = W2 + (size_t)(n0 + r0) * INTER + c0;
  const unsigned short* B1 = W2 + (size_t)(n0 + r1) * INTER + c1;
  unsigned short* lA0 = &As[(size_t)(wave * 16) * 64];
  unsigned short* lA1 = &As[(size_t)(wave * 16 + 8) * 64];
  unsigned short* lB0 = &Bs[(size_t)(wave * 16) * 64];
  unsigned short* lB1 = &Bs[(size_t)(wave * 16 + 8) * 64];
  for (int k0 = 0; k0 < INTER; k0 += 64) {
    __syncthreads();
    gl16(A0 + k0, lA0);
    gl16(A1 + k0, lA1);
    gl16(B0 + k0, lB0);
    gl16(B1 + k0, lB1);
    __syncthreads();
    #pragma unroll
    for (int ks = 0; ks < 2; ks++) {
      f16x8 af0 = *(const f16x8*)&As[swz(wm + lm, ks * 32 + quad * 8)];
      f16x8 af1 = *(const f16x8*)&As[swz(wm + 16 + lm, ks * 32 + quad * 8)];
      f16x8 bf0 = *(const f16x8*)&Bs[swz(wn + lm, ks * 32 + quad * 8)];
      f16x8 bf1 = *(const f16x8*)&Bs[swz(wn + 16 + lm, ks * 32 + quad * 8)];
      acc[0][0] = __builtin_amdgcn_mfma_f32_16x16x32_f16(af0, bf0, acc[0][0], 0, 0, 0);
      acc[0][1] = __builtin_amdgcn_mfma_f32_16x16x32_f16(af0, bf1, acc[0][1], 0, 0, 0);
      acc[1][0] = __builtin_amdgcn_mfma_f32_16x16x32_f16(af1, bf0, acc[1][0], 0, 0, 0);
      acc[1][1] = __builtin_amdgcn_mfma_f32_16x16x32_f16(af1, bf1, acc[1][1], 0, 0, 0);
    }
  }
  #pragma unroll
  for (int i = 0; i < 2; i++)
    #pragma unroll
    for (int j = 0; j < 2; j++) {
      int col = n0 + wn + j * 16 + lm;
      #pragma unroll
      for (int r = 0; r < 4; r++) {
        int g = m0 + wm + i * 16 + quad * 4 + r;
        if (g < count)
          Dout[(size_t)(base + g) * DIM + col] = f2h(acc[i][j][r]);
      }
    }
}

// ---------------- V transpose: vT[bh][d][s] = kvp[b*S+s][h*192+64+d] ----------------
// grid: (S_LEN/32, 128/32, 16), block 256
__launch_bounds__(256)
__global__ void vtrans_k(const unsigned short* __restrict__ kvp,
                         unsigned short* __restrict__ vT) {
  const int z = blockIdx.z, h = z & 7, b = z >> 3;
  const int s0 = blockIdx.x * 32, d0 = blockIdx.y * 32;
  __shared__ unsigned short ts[32][36];
  const int tid = threadIdx.x;
  const int r = tid >> 3, c4 = (tid & 7) * 4;
  ushort4 v = *(const ushort4*)(kvp + (size_t)(b * S_LEN + s0 + r) * KVP_W + h * 192 + 64 + d0 + c4);
  ts[r][c4] = v.x; ts[r][c4 + 1] = v.y; ts[r][c4 + 2] = v.z; ts[r][c4 + 3] = v.w;
  __syncthreads();
  ushort4 o;
  o.x = ts[c4][r]; o.y = ts[c4 + 1][r]; o.z = ts[c4 + 2][r]; o.w = ts[c4 + 3][r];
  *(ushort4*)(vT + ((size_t)z * 128 + d0 + r) * S_LEN + s0 + c4) = o;
}

// ---------------- attention, split-KV partials ----------------
// grid: (S/64 qt, 4 chunk, 16 bh), block 256 (4 waves; wave owns 16 query rows)
__launch_bounds__(256)
__global__ void attn_part_k(const unsigned short* __restrict__ q,
                            const unsigned short* __restrict__ kvp,
                            const float* __restrict__ kvb,
                            const unsigned short* __restrict__ vT,
                            float* __restrict__ opart, float* __restrict__ ml) {
  const int qt = blockIdx.x, ch = blockIdx.y, z = blockIdx.z;
  const int kt0 = ch * 4;
  if (kt0 > qt) return;
  const int h = z & 7, b = z >> 3;
  __shared__ __align__(16) _Float16 Ks[64][136];
  __shared__ __align__(16) _Float16 Vt[128][72];
  __shared__ __align__(16) _Float16 Ps[4][16][72];
  const int tid = threadIdx.x;
  const int lane = tid & 63, wave = tid >> 6;
  const int quad = lane >> 4, lm = lane & 15;
  const int qr0 = wave * 16;
  const float scale = 0.08838834764831845f;  // 128^-0.5
  const int tq = b * S_LEN + qt * 64;

  f16x8 qf[4];
  #pragma unroll
  for (int kc = 0; kc < 4; kc++)
    qf[kc] = *(const f16x8*)(q + (size_t)(tq + qr0 + lm) * 1024 + h * 128 + kc * 32 + quad * 8);

  float m_i[4], l_i[4];
  #pragma unroll
  for (int r = 0; r < 4; r++) { m_i[r] = -1e30f; l_i[r] = 0.f; }
  f32x4 o_acc[8] = {};

  const int kt_end = (kt0 + 3 < qt) ? (kt0 + 3) : qt;
  for (int kt = kt0; kt <= kt_end; ++kt) {
    const int tk = b * S_LEN + kt * 64;
    for (int i = tid; i < 64 * 8; i += 256) {
      int key = i & 63, g = i >> 6;
      *(f16x8*)&Ks[key][g * 8] =
          *(const f16x8*)(kvp + (size_t)(tk + key) * KVP_W + h * 192 + g * 8);
    }
    for (int i = tid; i < 64 * 16; i += 256) {
      int key = i & 63, g = i >> 6;
      float4 v = *(const float4*)(kvb + (size_t)(tk + key) * 320 + 256 + g * 4);
      ushort4 u;
      u.x = f2h(v.x); u.y = f2h(v.y); u.z = f2h(v.z); u.w = f2h(v.w);
      *(ushort4*)&Ks[key][64 + g * 4] = u;
    }
    for (int i = tid; i < 128 * 8; i += 256) {
      int d = i >> 3, seg = i & 7;
      *(f16x8*)&Vt[d][seg * 8] =
          *(const f16x8*)(vT + ((size_t)z * 128 + d) * S_LEN + kt * 64 + seg * 8);
    }
    __syncthreads();

    f32x4 sacc[4] = {};
    #pragma unroll
    for (int kc = 0; kc < 4; kc++) {
      #pragma unroll
      for (int jn = 0; jn < 4; jn++) {
        f16x8 bf = *(const f16x8*)&Ks[jn * 16 + lm][kc * 32 + quad * 8];
        sacc[jn] = __builtin_amdgcn_mfma_f32_16x16x32_f16(qf[kc], bf, sacc[jn], 0, 0, 0);
      }
    }
    const bool diag = (kt == qt);
    float p[4][4];
    float rowmax[4], rowsum[4];
    #pragma unroll
    for (int r = 0; r < 4; r++) rowmax[r] = -1e30f;
    #pragma unroll
    for (int jn = 0; jn < 4; jn++)
      #pragma unroll
      for (int r = 0; r < 4; r++) {
        float s = sacc[jn][r] * scale;
        if (diag && (jn * 16 + lm > qr0 + quad * 4 + r)) s = -1e30f;
        p[jn][r] = s;
        rowmax[r] = fmaxf(rowmax[r], s);
      }
    #pragma unroll
    for (int m = 1; m < 16; m <<= 1)
      #pragma unroll
      for (int r = 0; r < 4; r++)
        rowmax[r] = fmaxf(rowmax[r], __shfl_xor(rowmax[r], m, 64));
    float al[4];
    #pragma unroll
    for (int r = 0; r < 4; r++) {
      float mn = fmaxf(m_i[r], rowmax[r]);
      al[r] = __expf(m_i[r] - mn);
      m_i[r] = mn;
      rowsum[r] = 0.f;
    }
    #pragma unroll
    for (int jn = 0; jn < 4; jn++)
      #pragma unroll
      for (int r = 0; r < 4; r++) {
        float pv = __expf(p[jn][r] - m_i[r]);
        p[jn][r] = pv;
        rowsum[r] += pv;
      }
    #pragma unroll
    for (int m = 1; m < 16; m <<= 1)
      #pragma unroll
      for (int r = 0; r < 4; r++)
        rowsum[r] += __shfl_xor(rowsum[r], m, 64);
    #pragma unroll
    for (int r = 0; r < 4; r++) l_i[r] = l_i[r] * al[r] + rowsum[r];
    #pragma unroll
    for (int jn2 = 0; jn2 < 8; jn2++)
      #pragma unroll
      for (int r = 0; r < 4; r++) o_acc[jn2][r] *= al[r];
    #pragma unroll
    for (int jn = 0; jn < 4; jn++)
      #pragma unroll
      for (int r = 0; r < 4; r++)
        Ps[wave][quad * 4 + r][jn * 16 + lm] = (_Float16)p[jn][r];
    #pragma unroll
    for (int kc = 0; kc < 2; kc++) {
      f16x8 af = *(const f16x8*)&Ps[wave][lm][kc * 32 + quad * 8];
      #pragma unroll
      for (int jn2 = 0; jn2 < 8; jn2++) {
        f16x8 bf = *(const f16x8*)&Vt[jn2 * 16 + lm][kc * 32 + quad * 8];
        o_acc[jn2] = __builtin_amdgcn_mfma_f32_16x16x32_f16(af, bf, o_acc[jn2], 0, 0, 0);
      }
    }
    __syncthreads();
  }

  const size_t slot = ((size_t)z * 16 + qt) * 4 + ch;
  float* op = opart + slot * 8192;
  #pragma unroll
  for (int jn2 = 0; jn2 < 8; jn2++) {
    int col = jn2 * 16 + lm;
    #pragma unroll
    for (int r = 0; r < 4; r++) {
      int row = qr0 + quad * 4 + r;
      op[(size_t)row * 128 + col] = o_acc[jn2][r];
    }
  }
  if (lm == 0) {
    #pragma unroll
    for (int r = 0; r < 4; r++) {
      int row = qr0 + quad * 4 + r;
      ml[slot * 128 + row * 2] = m_i[r];
      ml[slot * 128 + row * 2 + 1] = l_i[r];
    }
  }
}

// ---------------- attention combine: rescale + sum partials -> atn f16 ----------------
// grid: (16 qt, 16 bh), block 256
__launch_bounds__(256)
__global__ void attn_comb_k(const float* __restrict__ opart, const float* __restrict__ ml,
                            unsigned short* __restrict__ o) {
  const int qt = blockIdx.x, z = blockIdx.y;
  const int h = z & 7, b = z >> 3;
  const int nch = (qt >> 2) + 1;
  const int tid = threadIdx.x;
  const int colg = tid & 31;            // cols colg*4 .. colg*4+3
  const int tq = b * S_LEN + qt * 64;
  const size_t slotbase = ((size_t)z * 16 + qt) * 4;
  for (int row = tid >> 5; row < 64; row += 8) {
    float mmax = -1e30f;
    #pragma unroll
    for (int c = 0; c < 4; c++)
      if (c < nch) mmax = fmaxf(mmax, ml[(slotbase + c) * 128 + row * 2]);
    float w[4];
    float lsum = 0.f;
    #pragma unroll
    for (int c = 0; c < 4; c++) {
      if (c < nch) {
        float mc = ml[(slotbase + c) * 128 + row * 2];
        float lc = ml[(slotbase + c) * 128 + row * 2 + 1];
        w[c] = __expf(mc - mmax);
        lsum += lc * w[c];
      } else w[c] = 0.f;
    }
    float inv = 1.f / lsum;
    float ax = 0.f, ay = 0.f, az = 0.f, aw = 0.f;
    #pragma unroll
    for (int c = 0; c < 4; c++) {
      if (c < nch) {
        const float* op = opart + (slotbase + c) * 8192 + (size_t)row * 128 + colg * 4;
        float4 v = *(const float4*)op;
        ax += w[c] * v.x; ay += w[c] * v.y; az += w[c] * v.z; aw += w[c] * v.w;
      }
    }
    ushort4 u;
    u.x = f2h(ax * inv); u.y = f2h(ay * inv);
    u.z = f2h(az * inv); u.w = f2h(aw * inv);
    *(ushort4*)(o + (size_t)(tq + row) * 1024 + h * 128 + colg * 4) = u;
  }
}

// ---------------- gate scores: logits[T][32] = xf32 @ gw^T, f32 ----------------
// grid: T/32 blocks, 256 threads
__launch_bounds__(256)
__global__ void scores_k(const float* __restrict__ xf, const float* __restrict__ gw,
                         float* __restrict__ sc) {
  __shared__ float xls[32][129];
  __shared__ float gls[32][129];
  const int t0 = blockIdx.x * 32;
  const int tid = threadIdx.x;
  const int lr = tid >> 3, lc = tid & 7;   // loader: row, col-group
  const int e = tid & 31, tg = tid >> 5;   // compute: expert, token-group
  float acc[4] = {};
  for (int k0 = 0; k0 < DIM; k0 += 128) {
    __syncthreads();
    #pragma unroll
    for (int it = 0; it < 4; it++) {
      int col = lc * 4 + it * 32;
      *(float4*)&xls[lr][col] = *(const float4*)(xf + (size_t)(t0 + lr) * DIM + k0 + col);
      *(float4*)&gls[lr][col] = *(const float4*)(gw + (size_t)lr * DIM + k0 + col);
    }
    __syncthreads();
    for (int d = 0; d < 128; d++) {
      float g = gls[e][d];
      #pragma unroll
      for (int j = 0; j < 4; j++)
        acc[j] += xls[tg * 4 + j][d] * g;
    }
  }
  #pragma unroll
  for (int j = 0; j < 4; j++)
    sc[(size_t)(t0 + tg * 4 + j) * N_EXP + e] = acc[j];
}

// ---------------- routing: one thread per token, bitmask selection ----------------
// grid: T/64 blocks, 64 threads
__launch_bounds__(64)
__global__ void route_k(const float* __restrict__ sc, const float* __restrict__ gb,
                        float* __restrict__ tw, int* __restrict__ tidx,
                        int* __restrict__ counts) {
  int t = blockIdx.x * 64 + threadIdx.x;
  if (t >= T_TOK) return;
  float orig[N_EXP], sb[N_EXP];
  #pragma unroll
  for (int i = 0; i < N_EXP; i++) {
    float s = 1.f / (1.f + __expf(-sc[(size_t)t * N_EXP + i]));
    orig[i] = s;
    sb[i] = s + gb[i];
  }
  float gsc[8];
  #pragma unroll
  for (int g = 0; g < 8; g++) {
    float m1 = -1e30f, m2 = -1e30f;
    #pragma unroll
    for (int j = 0; j < 4; j++) {
      float v = sb[g * 4 + j];
      if (v > m1) { m2 = m1; m1 = v; } else if (v > m2) m2 = v;
    }
    gsc[g] = m1 + m2;
  }
  unsigned gok = 0;
  #pragma unroll
  for (int it = 0; it < 4; it++) {
    int best = 0; float bv = -1e30f;
    #pragma unroll
    for (int g = 0; g < 8; g++)
      if (!((gok >> g) & 1u) && gsc[g] >= bv) { bv = gsc[g]; best = g; }
    gok |= 1u << best;
  }
  unsigned emask = 0;
  #pragma unroll
  for (int g = 0; g < 8; g++)
    if ((gok >> g) & 1u) emask |= 0xFu << (g * 4);
  unsigned taken = 0;
  int idx[TOPK]; float ow[TOPK]; float wsum = 0.f;
  #pragma unroll
  for (int k = 0; k < TOPK; k++) {
    int best = 0; float bv = -1e30f, bo = 0.f;
    #pragma unroll
    for (int i = 0; i < N_EXP; i++)
      if (((emask >> i) & 1u) && !((taken >> i) & 1u) && sb[i] >= bv) {
        bv = sb[i]; best = i; bo = orig[i];
      }
    taken |= 1u << best;
    idx[k] = best; ow[k] = bo; wsum += bo;
  }
  float inv = 1.f / (wsum + 1e-20f);
  #pragma unroll
  for (int k = 0; k < TOPK; k++) {
    tidx[t * TOPK + k] = idx[k];
    tw[t * TOPK + k] = ow[k] * inv;
    atomicAdd(&counts[idx[k]], 1);
  }
}

__global__ void scan_k(const int* __restrict__ counts, int* __restrict__ offs) {
  if (threadIdx.x == 0 && blockIdx.x == 0) {
    int acc = 0;
    for (int e = 0; e < N_EXP; e++) { offs[e] = acc; acc += counts[e]; }
    offs[N_EXP] = acc;
  }
}

__launch_bounds__(256)
__global__ void scatter_k(const int* __restrict__ tidx, const int* __restrict__ offs,
                          int* __restrict__ fill, int* __restrict__ perm,
                          int* __restrict__ posOf) {
  int t = blockIdx.x * 256 + threadIdx.x;
  if (t >= T_TOK) return;
  for (int j = 0; j < TOPK; j++) {
    int e = tidx[t * TOPK + j];
    int pos = atomicAdd(&fill[e], 1);
    int p = offs[e] + pos;
    perm[p] = t * TOPK + j;
    posOf[t * TOPK + j] = p;
  }
}

// ---------------- final combine ----------------
__launch_bounds__(256)
__global__ void final_gather_k(const float* __restrict__ x1,
                               const unsigned short* __restrict__ dbuf,
                               const unsigned short* __restrict__ sdbuf,
                               const int* __restrict__ posOf,
                               const float* __restrict__ tw,
                               float* __restrict__ out) {
  int t = blockIdx.x;
  int c0 = threadIdx.x * 4;
  int p0 = posOf[t * 4 + 0], p1 = posOf[t * 4 + 1];
  int p2 = posOf[t * 4 + 2], p3 = posOf[t * 4 + 3];
  float w0 = tw[t * 4 + 0], w1 = tw[t * 4 + 1];
  float w2 = tw[t * 4 + 2], w3 = tw[t * 4 + 3];
  size_t tb = (size_t)t * DIM;
  #pragma unroll
  for (int i = 0; i < 4; i++) {
    int c = c0 + i;
    float v = x1[tb + c] + h2f(sdbuf[tb + c])
            + w0 * h2f(dbuf[(size_t)p0 * DIM + c])
            + w1 * h2f(dbuf[(size_t)p1 * DIM + c])
            + w2 * h2f(dbuf[(size_t)p2 * DIM + c])
            + w3 * h2f(dbuf[(size_t)p3 * DIM + c]);
    out[tb + c] = v;
  }
}

// ---------------- host launch ----------------
extern "C" void kernel_launch(void* const* d_in, const int* in_sizes, int n_in,
                              void* d_out, int out_size, void* d_ws, size_t ws_size,
                              hipStream_t stream) {
  const float* x        = (const float*)d_in[0];
  const float* norm_attn= (const float*)d_in[1];
  const float* wq       = (const float*)d_in[2];
  const float* wkv_a    = (const float*)d_in[3];
  const float* kv_norm_w= (const float*)d_in[4];
  const float* wkv_b    = (const float*)d_in[5];
  const float* wo       = (const float*)d_in[6];
  const float* norm_moe = (const float*)d_in[7];
  const float* gate_w   = (const float*)d_in[8];
  const float* gate_b   = (const float*)d_in[9];
  const float* ew1      = (const float*)d_in[10];
  const float* ew2      = (const float*)d_in[11];
  const float* ew3      = (const float*)d_in[12];
  const float* sw1      = (const float*)d_in[13];
  const float* sw2      = (const float*)d_in[14];
  const float* sw3      = (const float*)d_in[15];
  float* out = (float*)d_out;

  char* wp = (char*)d_ws;
  auto alloc = [&](size_t bytes) -> char* {
    char* r = wp;
    wp += (bytes + 255) & ~(size_t)255;
    return r;
  };
  typedef unsigned short us;
  us* wqT   = (us*)alloc(1048576 * 2);
  us* wkvaT = (us*)alloc(327680 * 2);
  us* wkvbT = (us*)alloc(393216 * 2);
  us* woT   = (us*)alloc(1048576 * 2);
  us* ew1T  = (us*)alloc((size_t)16777216 * 2);
  us* ew3T  = (us*)alloc((size_t)16777216 * 2);
  us* ew2T  = (us*)alloc((size_t)16777216 * 2);
  us* sw1T  = (us*)alloc(524288 * 2);
  us* sw3T  = (us*)alloc(524288 * 2);
  us* sw2T  = (us*)alloc(524288 * 2);
  us* xb    = (us*)alloc(2097152 * 2);   // xn, later xfb
  us* cn    = (us*)alloc(524288 * 2);
  us* atn   = (us*)alloc(2097152 * 2);
  us* dbuf  = (us*)alloc((size_t)8388608 * 2);
  us* qb    = (us*)alloc(2097152 * 4);    // f16 q; later sdbuf aliases
  float* kvb  = (float*)alloc(655360 * 4);
  us* kvp   = (us*)alloc(3145728 * 4);    // f16 kvp; later hbuf+hs alias
  float* x1   = (float*)alloc(2097152 * 4);
  float* xf32 = (float*)alloc(2097152 * 4);
  float* scb  = (float*)alloc(65536 * 4);
  float* twb  = (float*)alloc(8192 * 4);
  int* tidx   = (int*)alloc(8192 * 4);
  int* perm   = (int*)alloc(8192 * 4);
  int* posOf  = (int*)alloc(8192 * 4);
  int* counts = (int*)alloc(64 * 4);
  int* offs   = (int*)alloc(64 * 4);
  int* fill   = (int*)alloc(64 * 4);
  us* vT     = (us*)alloc((size_t)2 * 8 * 128 * 1024 * 2);   // 4 MB
  float* mlb = (float*)alloc((size_t)1024 * 128 * 4);        // 512 KB
  us* sdbuf = qb;
  us* hbuf  = kvp;
  us* hs    = hbuf + (size_t)8192 * 512;
  // attention partials (32 MB) alias ew1T: written/read before ew1 tcvt runs
  float* opart = (float*)ew1T;

  // small weight transposes needed for MLA path
  tcvt_k<<<dim3(32, 32, 1), 256, 0, stream>>>(wq, wqT, 1024, 1024);
  tcvt_k<<<dim3(10, 32, 1), 256, 0, stream>>>(wkv_a, wkvaT, 1024, 320);
  tcvt_k<<<dim3(48, 8, 1), 256, 0, stream>>>(wkv_b, wkvbT, 256, 1536);
  tcvt_k<<<dim3(32, 32, 1), 256, 0, stream>>>(wo, woT, 1024, 1024);

  // ---- MLA ----
  rmsnorm_k<<<T_TOK, 256, 0, stream>>>(x, DIM, DIM, norm_attn, xb, nullptr, DIM);
  gemm_bt_k<0, 1><<<dim3(16, 32), 256, 0, stream>>>(xb, wqT, nullptr, qb, 1024, 1024);
  gemm_bt_k<0, 0><<<dim3(5, 32), 256, 0, stream>>>(xb, wkvaT, nullptr, kvb, 320, 1024);
  rmsnorm_k<<<T_TOK, 256, 0, stream>>>(kvb, 320, KV_LORA, kv_norm_w, cn, nullptr, KV_LORA);
  gemm_bt_k<0, 1><<<dim3(24, 32), 256, 0, stream>>>(cn, wkvbT, nullptr, kvp, 1536, 256);
  vtrans_k<<<dim3(32, 4, 16), 256, 0, stream>>>(kvp, vT);
  attn_part_k<<<dim3(16, 4, 16), 256, 0, stream>>>(qb, kvp, kvb, vT, opart, mlb);
  attn_comb_k<<<dim3(16, 16), 256, 0, stream>>>(opart, mlb, atn);
  gemm_bt_k<1, 0><<<dim3(16, 32), 256, 0, stream>>>(atn, woT, x, x1, 1024, 1024);

  // expert / shared weight conversion (after attention: opart aliased ew1T)
  tcvt_k<<<dim3(16, 32, 32), 256, 0, stream>>>(ew1, ew1T, 1024, 512);
  tcvt_k<<<dim3(16, 32, 32), 256, 0, stream>>>(ew3, ew3T, 1024, 512);
  tcvt_k<<<dim3(32, 16, 32), 256, 0, stream>>>(ew2, ew2T, 512, 1024);
  tcvt_k<<<dim3(16, 32, 1), 256, 0, stream>>>(sw1, sw1T, 1024, 512);
  tcvt_k<<<dim3(16, 32, 1), 256, 0, stream>>>(sw3, sw3T, 1024, 512);
  tcvt_k<<<dim3(32, 16, 1), 256, 0, stream>>>(sw2, sw2T, 512, 1024);

  // ---- MoE (shared expert fused as z == N_EXP) ----
  rmsnorm_k<<<T_TOK, 256, 0, stream>>>(x1, DIM, DIM, norm_moe, xb, xf32, DIM);
  zero_counters_k<<<1, 64, 0, stream>>>(counts, fill);
  scores_k<<<T_TOK / 32, 256, 0, stream>>>(xf32, gate_w, scb);
  route_k<<<T_TOK / 64, 64, 0, stream>>>(scb, gate_b, twb, tidx, counts);
  scan_k<<<1, 1, 0, stream>>>(counts, offs);
  scatter_k<<<(T_TOK + 255) / 256, 256, 0, stream>>>(tidx, offs, fill, perm, posOf);
  moe_up_k<<<dim3(8, 32, N_EXP + 1), 256, 0, stream>>>(xb, ew1T, ew3T, sw1T, sw3T,
                                                       hbuf, hs, perm, offs);
  moe_down_k<<<dim3(16, 32, N_EXP + 1), 256, 0, stream>>>(hbuf, hs, ew2T, sw2T,
                                                          dbuf, sdbuf, offs);

  final_gather_k<<<T_TOK, 256, 0, stream>>>(x1, dbuf, sdbuf, posOf, twb, out);
}